// Round 1
// baseline (1220.123 us; speedup 1.0000x reference)
//
#include <hip/hip_runtime.h>
#include <hip/hip_bf16.h>
#include <math.h>

#define D_MODEL 512
#define D_INNER 1024
#define D_STATE 128
#define CONV_DIM (D_INNER + 2*D_STATE)        // 1280
#define D_IN_PROJ (2*D_INNER + 2*D_STATE + 1) // 2305
#define NPROJ 2304                            // z + xBC cols (dt col handled by GEMV)
#define BATCH 8
#define SEQ 2048
#define NROWS (BATCH*SEQ)                     // 16384
#define EPS_RMS 1e-5f

typedef __hip_bfloat16 bf16;
typedef __attribute__((ext_vector_type(8))) short short8;  // 8 bf16 = 4 VGPRs (MFMA A/B frag)
typedef __attribute__((ext_vector_type(4))) float f32x4;   // MFMA C/D frag

__device__ __forceinline__ float fbf(bf16 v) { return __bfloat162float(v); }
__device__ __forceinline__ bf16 tbf(float v) { return __float2bfloat16(v); }

// ---------- elementwise fp32 -> bf16 convert (flat, n % 4 == 0) ----------
__global__ void k_cvt_bf16(const float* __restrict__ s, bf16* __restrict__ d, int n) {
    int i = (blockIdx.x * 256 + threadIdx.x) * 4;
    if (i >= n) return;
    float4 v = *(const float4*)(s + i);
    d[i+0] = tbf(v.x); d[i+1] = tbf(v.y); d[i+2] = tbf(v.z); d[i+3] = tbf(v.w);
}

// ---------- transpose + convert: dst[r][c] = bf16(src[c*sstride + r]) ----------
// grid: (C/32, R/32), block (32,8)
__global__ void k_transpose_cvt(const float* __restrict__ src, bf16* __restrict__ dst,
                                int R, int C, int sstride) {
    __shared__ float tile[32][33];
    int c0 = blockIdx.x * 32, r0 = blockIdx.y * 32;
    int tx = threadIdx.x, ty = threadIdx.y;
    #pragma unroll
    for (int i = 0; i < 32; i += 8)
        tile[ty + i][tx] = src[(size_t)(c0 + ty + i) * sstride + (r0 + tx)];
    __syncthreads();
    #pragma unroll
    for (int i = 0; i < 32; i += 8)
        dst[(size_t)(r0 + ty + i) * C + (c0 + tx)] = tbf(tile[tx][ty + i]);
}

// ---------- NT GEMM via MFMA 16x16x32 bf16: C[M,N] = A[M,K] @ Bt[N,K]^T ----------
// 128x128 block tile, 256 threads (2x2 waves of 64x64), BK=64, LDS pad +8 bf16.
template<int OUTBF>
__global__ __launch_bounds__(256) void k_gemm_nt(
    const bf16* __restrict__ A, const bf16* __restrict__ Bt,
    void* __restrict__ C, int M, int N, int K)
{
    constexpr int TM = 128, TN = 128, BK = 64, LDK = BK + 8;
    __shared__ __align__(16) bf16 As[TM][LDK];
    __shared__ __align__(16) bf16 Bs[TN][LDK];
    const int tid  = threadIdx.x;
    const int lane = tid & 63;
    const int wave = tid >> 6;
    const int wm   = (wave & 1) * 64;
    const int wn   = (wave >> 1) * 64;
    const int lr   = lane & 15;
    const int quad = lane >> 4;
    const size_t bm = (size_t)blockIdx.x * TM;
    const size_t bn = (size_t)blockIdx.y * TN;

    f32x4 acc[4][4];
    #pragma unroll
    for (int i = 0; i < 4; ++i)
        #pragma unroll
        for (int j = 0; j < 4; ++j)
            acc[i][j] = (f32x4){0.f, 0.f, 0.f, 0.f};

    for (int k0 = 0; k0 < K; k0 += BK) {
        __syncthreads();
        // stage A,B tiles: 128 rows x 64 bf16 each; 1024 16B-chunks / 256 thr = 4 each
        #pragma unroll
        for (int i = 0; i < 4; ++i) {
            int c   = tid + 256 * i;
            int r   = c >> 3;
            int col = (c & 7) << 3;
            *(uint4*)(&As[r][col]) = *(const uint4*)(A  + (bm + r) * K + k0 + col);
            *(uint4*)(&Bs[r][col]) = *(const uint4*)(Bt + (bn + r) * K + k0 + col);
        }
        __syncthreads();
        #pragma unroll
        for (int ks = 0; ks < BK; ks += 32) {
            short8 af[4], bg[4];
            #pragma unroll
            for (int i = 0; i < 4; ++i)
                af[i] = *(const short8*)(&As[wm + i * 16 + lr][ks + quad * 8]);
            #pragma unroll
            for (int j = 0; j < 4; ++j)
                bg[j] = *(const short8*)(&Bs[wn + j * 16 + lr][ks + quad * 8]);
            #pragma unroll
            for (int i = 0; i < 4; ++i)
                #pragma unroll
                for (int j = 0; j < 4; ++j)
                    acc[i][j] = __builtin_amdgcn_mfma_f32_16x16x32_bf16(af[i], bg[j], acc[i][j], 0, 0, 0);
        }
    }
    // epilogue: C/D layout col=lane&15, row=quad*4+reg (verified m89/m91)
    #pragma unroll
    for (int i = 0; i < 4; ++i)
        #pragma unroll
        for (int j = 0; j < 4; ++j)
            #pragma unroll
            for (int r = 0; r < 4; ++r) {
                size_t row = bm + wm + i * 16 + quad * 4 + r;
                size_t col = bn + wn + j * 16 + lr;
                float v = acc[i][j][r];
                if (OUTBF) ((bf16*)C)[row * N + col]  = tbf(v);
                else       ((float*)C)[row * N + col] = v;
            }
}

// ---------- dt GEMV + softplus + dA: one wave per row ----------
__global__ void k_dt(const float* __restrict__ x, const float* __restrict__ W_in,
                     const float* __restrict__ dt_bias, const float* __restrict__ A_log,
                     float* __restrict__ dts, float* __restrict__ dAv)
{
    int row  = blockIdx.x * 4 + (threadIdx.x >> 6);
    int lane = threadIdx.x & 63;
    const float* xr = x + (size_t)row * D_MODEL;
    float s = 0.f;
    #pragma unroll
    for (int i = 0; i < D_MODEL / 64; ++i)
        s += xr[lane + i * 64] * W_in[(size_t)(lane + i * 64) * D_IN_PROJ + 2304];
    #pragma unroll
    for (int off = 32; off; off >>= 1) s += __shfl_xor(s, off);
    if (lane == 0) {
        float raw = s + dt_bias[0];
        float sp  = raw > 20.f ? raw : log1pf(expf(raw));
        dts[row] = sp;
        dAv[row] = expf(-expf(A_log[0]) * sp);   // exp(dt * A), A = -exp(A_log)
    }
}

// ---------- causal depthwise conv(4) + bias + SiLU ----------
// grid (CONV_DIM/256, NROWS)
__global__ void k_conv(const bf16* __restrict__ zxbc, const float* __restrict__ conv_w,
                       const float* __restrict__ conv_b, bf16* __restrict__ xBCa)
{
    int c   = blockIdx.x * 256 + threadIdx.x;   // 0..1279
    int row = blockIdx.y;                       // b*SEQ + t
    int t   = row & (SEQ - 1);
    float acc = conv_b[c];
    #pragma unroll
    for (int j = 0; j < 4; ++j) {
        int tt = t - 3 + j;
        if (tt >= 0) {
            float xv = fbf(zxbc[(size_t)(row - 3 + j) * NPROJ + D_INNER + c]);
            acc = fmaf(xv, conv_w[c * 4 + j], acc);
        }
    }
    float v = acc / (1.f + expf(-acc));         // silu
    xBCa[(size_t)row * CONV_DIM + c] = tbf(v);
}

// ---------- sequential selective scan ----------
// grid (64, BATCH): block covers 16 channels; thread=(ngrp=tid&15 -> 8 states, pi=tid>>4).
// y includes + D * x_ssm.
__global__ __launch_bounds__(256) void k_scan(
    const bf16* __restrict__ xBCa, const float* __restrict__ dts,
    const float* __restrict__ dAv, const float* __restrict__ Dp,
    float* __restrict__ y)
{
    const int pb   = blockIdx.x;
    const int b    = blockIdx.y;
    const int tid  = threadIdx.x;
    const int ngrp = tid & 15;
    const int pi   = tid >> 4;
    const int p    = pb * 16 + pi;
    const float D0 = Dp[0];

    __shared__ float Bsh[8][128];
    __shared__ float Csh[8][128];
    __shared__ float xsh[8][16];
    __shared__ float dt_s[8], dA_s[8];

    float h[8];
    #pragma unroll
    for (int j = 0; j < 8; ++j) h[j] = 0.f;

    const size_t rowbase = (size_t)b * SEQ;
    for (int t0 = 0; t0 < SEQ; t0 += 8) {
        __syncthreads();
        for (int i = tid; i < 1024; i += 256) {
            int tt = i >> 7, n = i & 127;
            size_t r = (rowbase + t0 + tt) * CONV_DIM;
            Bsh[tt][n] = fbf(xBCa[r + D_INNER + n]);
            Csh[tt][n] = fbf(xBCa[r + D_INNER + D_STATE + n]);
        }
        if (tid < 128) {
            int tt = tid >> 4, pj = tid & 15;
            xsh[tt][pj] = fbf(xBCa[(rowbase + t0 + tt) * CONV_DIM + pb * 16 + pj]);
        }
        if (tid < 8) {
            dt_s[tid] = dts[rowbase + t0 + tid];
            dA_s[tid] = dAv[rowbase + t0 + tid];
        }
        __syncthreads();
        #pragma unroll
        for (int tt = 0; tt < 8; ++tt) {
            float dav = dA_s[tt];
            float xv  = xsh[tt][pi];
            float dtx = dt_s[tt] * xv;
            const float4* bp = (const float4*)&Bsh[tt][ngrp * 8];
            const float4* cp = (const float4*)&Csh[tt][ngrp * 8];
            float a0 = 0.f;
            #pragma unroll
            for (int v = 0; v < 2; ++v) {
                float4 bv = bp[v], cv = cp[v];
                h[v*4+0] = fmaf(h[v*4+0], dav, dtx * bv.x); a0 = fmaf(h[v*4+0], cv.x, a0);
                h[v*4+1] = fmaf(h[v*4+1], dav, dtx * bv.y); a0 = fmaf(h[v*4+1], cv.y, a0);
                h[v*4+2] = fmaf(h[v*4+2], dav, dtx * bv.z); a0 = fmaf(h[v*4+2], cv.z, a0);
                h[v*4+3] = fmaf(h[v*4+3], dav, dtx * bv.w); a0 = fmaf(h[v*4+3], cv.w, a0);
            }
            #pragma unroll
            for (int off = 1; off <= 8; off <<= 1) a0 += __shfl_xor(a0, off);
            if (ngrp == 0)
                y[(rowbase + t0 + tt) * D_INNER + p] = a0 + D0 * xv;
        }
    }
}

// ---------- gate (silu(z)) + RMSNorm -> bf16 ----------
// one block (256 thr) per row; thread handles 4 contiguous channels
__global__ __launch_bounds__(256) void k_gate_norm(
    const float* __restrict__ y, const bf16* __restrict__ zxbc,
    const float* __restrict__ norm_w, bf16* __restrict__ yb)
{
    int row = blockIdx.x;
    int tid = threadIdx.x;
    const float* yr = y + (size_t)row * D_INNER;
    const bf16*  zr = zxbc + (size_t)row * NPROJ;
    float4 v = *(const float4*)(yr + tid * 4);
    float z0 = fbf(zr[tid*4+0]), z1 = fbf(zr[tid*4+1]);
    float z2 = fbf(zr[tid*4+2]), z3 = fbf(zr[tid*4+3]);
    v.x *= z0 / (1.f + expf(-z0));
    v.y *= z1 / (1.f + expf(-z1));
    v.z *= z2 / (1.f + expf(-z2));
    v.w *= z3 / (1.f + expf(-z3));
    float ss = v.x*v.x + v.y*v.y + v.z*v.z + v.w*v.w;
    #pragma unroll
    for (int off = 32; off; off >>= 1) ss += __shfl_xor(ss, off);
    __shared__ float wsum[4];
    if ((tid & 63) == 0) wsum[tid >> 6] = ss;
    __syncthreads();
    float tot   = wsum[0] + wsum[1] + wsum[2] + wsum[3];
    float scale = rsqrtf(tot * (1.f / D_INNER) + EPS_RMS);
    yb[(size_t)row * D_INNER + tid*4+0] = tbf(v.x * scale * norm_w[tid*4+0]);
    yb[(size_t)row * D_INNER + tid*4+1] = tbf(v.y * scale * norm_w[tid*4+1]);
    yb[(size_t)row * D_INNER + tid*4+2] = tbf(v.z * scale * norm_w[tid*4+2]);
    yb[(size_t)row * D_INNER + tid*4+3] = tbf(v.w * scale * norm_w[tid*4+3]);
}

extern "C" void kernel_launch(void* const* d_in, const int* in_sizes, int n_in,
                              void* d_out, int out_size, void* d_ws, size_t ws_size,
                              hipStream_t stream)
{
    const float* x       = (const float*)d_in[0];
    const float* rnn     = (const float*)d_in[1];
    const float* W_in    = (const float*)d_in[2];
    const float* conv_w  = (const float*)d_in[3];
    const float* conv_b  = (const float*)d_in[4];
    const float* dt_bias = (const float*)d_in[5];
    const float* A_log   = (const float*)d_in[6];
    const float* Dp      = (const float*)d_in[7];
    const float* norm_w  = (const float*)d_in[8];
    const float* W_out   = (const float*)d_in[9];
    float* out = (float*)d_out;

    char* ws = (char*)d_ws;
    size_t off = 0;
    auto alloc = [&](size_t bytes) { void* p = ws + off; off += (bytes + 255) & ~255ULL; return p; };
    bf16*  xb      = (bf16*) alloc((size_t)NROWS * D_MODEL * 2);
    bf16*  W_inbT  = (bf16*) alloc((size_t)NPROJ * D_MODEL * 2);   // [n=2304][k=512]
    bf16*  W_outbT = (bf16*) alloc((size_t)D_MODEL * D_INNER * 2); // [n=512][k=1024]
    bf16*  zxbc    = (bf16*) alloc((size_t)NROWS * NPROJ * 2);
    float* dts     = (float*)alloc((size_t)NROWS * 4);
    float* dAv     = (float*)alloc((size_t)NROWS * 4);
    bf16*  xBCa    = (bf16*) alloc((size_t)NROWS * CONV_DIM * 2);
    float* yf      = (float*)alloc((size_t)NROWS * D_INNER * 4);
    bf16*  yb      = (bf16*) alloc((size_t)NROWS * D_INNER * 2);
    // total ~238.4 MB

    // 1. converts / transposes / dt GEMV
    k_cvt_bf16<<<(NROWS * D_MODEL / 4 + 255) / 256, 256, 0, stream>>>(x, xb, NROWS * D_MODEL);
    k_transpose_cvt<<<dim3(D_MODEL / 32, NPROJ / 32), dim3(32, 8), 0, stream>>>(
        W_in, W_inbT, NPROJ, D_MODEL, D_IN_PROJ);
    k_transpose_cvt<<<dim3(D_INNER / 32, D_MODEL / 32), dim3(32, 8), 0, stream>>>(
        W_out, W_outbT, D_MODEL, D_INNER, D_MODEL);
    k_dt<<<NROWS / 4, 256, 0, stream>>>(x, W_in, dt_bias, A_log, dts, dAv);

    // 2. in-projection GEMM (z + xBC), bf16 out
    k_gemm_nt<1><<<dim3(NROWS / 128, NPROJ / 128), 256, 0, stream>>>(
        xb, W_inbT, zxbc, NROWS, NPROJ, D_MODEL);

    // 3. causal depthwise conv + silu
    k_conv<<<dim3(CONV_DIM / 256, NROWS), 256, 0, stream>>>(zxbc, conv_w, conv_b, xBCa);

    // 4. selective scan
    k_scan<<<dim3(64, BATCH), 256, 0, stream>>>(xBCa, dts, dAv, Dp, yf);

    // 5. gate + RMSNorm
    k_gate_norm<<<NROWS, 256, 0, stream>>>(yf, zxbc, norm_w, yb);

    // 6. out-projection GEMM, fp32 out -> d_out
    k_gemm_nt<0><<<dim3(NROWS / 128, D_MODEL / 128), 256, 0, stream>>>(
        yb, W_outbT, out, NROWS, D_MODEL, D_INNER);

    // 7. rnn_state passthrough
    hipMemcpyAsync(out + (size_t)NROWS * D_MODEL, rnn,
                   (size_t)BATCH * D_MODEL * sizeof(float),
                   hipMemcpyDeviceToDevice, stream);
}

// Round 2
// 493.957 us; speedup vs baseline: 2.4701x; 2.4701x over previous
//
#include <hip/hip_runtime.h>
#include <hip/hip_bf16.h>
#include <math.h>

#define D_MODEL 512
#define D_INNER 1024
#define D_STATE 128
#define CONV_DIM (D_INNER + 2*D_STATE)        // 1280
#define D_IN_PROJ (2*D_INNER + 2*D_STATE + 1) // 2305
#define NPROJ 2304                            // z + xBC cols (dt col via GEMV)
#define BATCH 8
#define SEQ 2048
#define NROWS (BATCH*SEQ)                     // 16384
#define CHUNK 128
#define NCHUNK (NROWS/CHUNK)                  // 128 total (16 per batch)
#define EPS_RMS 1e-5f

typedef __hip_bfloat16 bf16;
typedef __attribute__((ext_vector_type(8))) short short8;
typedef __attribute__((ext_vector_type(4))) float f32x4;

__device__ __forceinline__ float fbf(bf16 v) { return __bfloat162float(v); }
__device__ __forceinline__ bf16 tbf(float v) { return __float2bfloat16(v); }

// ---------- fp32 -> bf16 convert ----------
__global__ void k_cvt_bf16(const float* __restrict__ s, bf16* __restrict__ d, int n) {
    int i = (blockIdx.x * 256 + threadIdx.x) * 4;
    if (i >= n) return;
    float4 v = *(const float4*)(s + i);
    d[i+0] = tbf(v.x); d[i+1] = tbf(v.y); d[i+2] = tbf(v.z); d[i+3] = tbf(v.w);
}

// ---------- transpose + convert: dst[r][c] = bf16(src[c*sstride + r]) ----------
__global__ void k_transpose_cvt(const float* __restrict__ src, bf16* __restrict__ dst,
                                int R, int C, int sstride) {
    __shared__ float tile[32][33];
    int c0 = blockIdx.x * 32, r0 = blockIdx.y * 32;
    int tx = threadIdx.x, ty = threadIdx.y;
    #pragma unroll
    for (int i = 0; i < 32; i += 8)
        tile[ty + i][tx] = src[(size_t)(c0 + ty + i) * sstride + (r0 + tx)];
    __syncthreads();
    #pragma unroll
    for (int i = 0; i < 32; i += 8)
        dst[(size_t)(r0 + ty + i) * C + (c0 + tx)] = tbf(tile[tx][ty + i]);
}

// ---------- batched NT GEMM, 128x128 tile, BK=64 ----------
// C[bi][M][N] = A[bi][M][K] @ Bt[bi][N][K]^T   (ACC: +=)
template<int OUTBF, int ACC>
__global__ __launch_bounds__(256) void k_bgemm(
    const bf16* __restrict__ A, int lda, size_t sA,
    const bf16* __restrict__ Bt, int ldb, size_t sB,
    void* __restrict__ Cv, int ldc, size_t sC, int K)
{
    constexpr int BK = 64, LDK = BK + 8;
    __shared__ __align__(16) bf16 As[128][LDK];
    __shared__ __align__(16) bf16 Bs[128][LDK];
    const int tid = threadIdx.x, lane = tid & 63, wave = tid >> 6;
    const int wm = (wave & 1) * 64, wn = (wave >> 1) * 64;
    const int lr = lane & 15, quad = lane >> 4;
    const size_t bm = (size_t)blockIdx.x * 128;
    const size_t bn = (size_t)blockIdx.y * 128;
    const size_t bi = blockIdx.z;
    A  += bi * sA;
    Bt += bi * sB;

    f32x4 acc[4][4];
    #pragma unroll
    for (int i = 0; i < 4; ++i)
        #pragma unroll
        for (int j = 0; j < 4; ++j) acc[i][j] = (f32x4){0.f,0.f,0.f,0.f};

    for (int k0 = 0; k0 < K; k0 += BK) {
        __syncthreads();
        #pragma unroll
        for (int i = 0; i < 4; ++i) {
            int c = tid + 256 * i;
            int r = c >> 3, col = (c & 7) << 3;
            *(uint4*)(&As[r][col]) = *(const uint4*)(A  + (bm + r) * lda + k0 + col);
            *(uint4*)(&Bs[r][col]) = *(const uint4*)(Bt + (bn + r) * ldb + k0 + col);
        }
        __syncthreads();
        #pragma unroll
        for (int ks = 0; ks < BK; ks += 32) {
            short8 af[4], bg[4];
            #pragma unroll
            for (int i = 0; i < 4; ++i)
                af[i] = *(const short8*)(&As[wm + i*16 + lr][ks + quad*8]);
            #pragma unroll
            for (int j = 0; j < 4; ++j)
                bg[j] = *(const short8*)(&Bs[wn + j*16 + lr][ks + quad*8]);
            #pragma unroll
            for (int i = 0; i < 4; ++i)
                #pragma unroll
                for (int j = 0; j < 4; ++j)
                    acc[i][j] = __builtin_amdgcn_mfma_f32_16x16x32_bf16(af[i], bg[j], acc[i][j], 0,0,0);
        }
    }
    #pragma unroll
    for (int i = 0; i < 4; ++i)
        #pragma unroll
        for (int j = 0; j < 4; ++j)
            #pragma unroll
            for (int r = 0; r < 4; ++r) {
                size_t row = bm + wm + i*16 + quad*4 + r;
                size_t col = bn + wn + j*16 + lr;
                float v = acc[i][j][r];
                if (OUTBF) {
                    bf16* C = (bf16*)Cv + bi * sC;
                    C[row * ldc + col] = tbf(v);
                } else {
                    float* C = (float*)Cv + bi * sC;
                    if (ACC) C[row * ldc + col] += v;
                    else     C[row * ldc + col] = v;
                }
            }
}

// ---------- GEMM1 with split output: cols<1024 -> zb[row][1024], else xBCin[row][1280] ----------
__global__ __launch_bounds__(256) void k_gemm_in(
    const bf16* __restrict__ A, const bf16* __restrict__ Bt,
    bf16* __restrict__ zb, bf16* __restrict__ xBCin, int K)
{
    constexpr int BK = 64, LDK = BK + 8;
    __shared__ __align__(16) bf16 As[128][LDK];
    __shared__ __align__(16) bf16 Bs[128][LDK];
    const int tid = threadIdx.x, lane = tid & 63, wave = tid >> 6;
    const int wm = (wave & 1) * 64, wn = (wave >> 1) * 64;
    const int lr = lane & 15, quad = lane >> 4;
    const size_t bm = (size_t)blockIdx.x * 128;
    const int bn = blockIdx.y * 128;

    f32x4 acc[4][4];
    #pragma unroll
    for (int i = 0; i < 4; ++i)
        #pragma unroll
        for (int j = 0; j < 4; ++j) acc[i][j] = (f32x4){0.f,0.f,0.f,0.f};

    for (int k0 = 0; k0 < K; k0 += BK) {
        __syncthreads();
        #pragma unroll
        for (int i = 0; i < 4; ++i) {
            int c = tid + 256 * i;
            int r = c >> 3, col = (c & 7) << 3;
            *(uint4*)(&As[r][col]) = *(const uint4*)(A  + (bm + r) * K + k0 + col);
            *(uint4*)(&Bs[r][col]) = *(const uint4*)(Bt + ((size_t)bn + r) * K + k0 + col);
        }
        __syncthreads();
        #pragma unroll
        for (int ks = 0; ks < BK; ks += 32) {
            short8 af[4], bg[4];
            #pragma unroll
            for (int i = 0; i < 4; ++i)
                af[i] = *(const short8*)(&As[wm + i*16 + lr][ks + quad*8]);
            #pragma unroll
            for (int j = 0; j < 4; ++j)
                bg[j] = *(const short8*)(&Bs[wn + j*16 + lr][ks + quad*8]);
            #pragma unroll
            for (int i = 0; i < 4; ++i)
                #pragma unroll
                for (int j = 0; j < 4; ++j)
                    acc[i][j] = __builtin_amdgcn_mfma_f32_16x16x32_bf16(af[i], bg[j], acc[i][j], 0,0,0);
        }
    }
    #pragma unroll
    for (int i = 0; i < 4; ++i)
        #pragma unroll
        for (int j = 0; j < 4; ++j)
            #pragma unroll
            for (int r = 0; r < 4; ++r) {
                size_t row = bm + wm + i*16 + quad*4 + r;
                int col = bn + wn + j*16 + lr;
                float v = acc[i][j][r];
                if (col < D_INNER) zb[row * D_INNER + col] = tbf(v);
                else xBCin[row * CONV_DIM + (col - D_INNER)] = tbf(v);
            }
}

// ---------- dt GEMV + softplus ----------
__global__ void k_dt(const float* __restrict__ x, const float* __restrict__ W_in,
                     const float* __restrict__ dt_bias, float* __restrict__ dts)
{
    int row  = blockIdx.x * 4 + (threadIdx.x >> 6);
    int lane = threadIdx.x & 63;
    const float* xr = x + (size_t)row * D_MODEL;
    float s = 0.f;
    #pragma unroll
    for (int i = 0; i < D_MODEL / 64; ++i)
        s += xr[lane + i * 64] * W_in[(size_t)(lane + i * 64) * D_IN_PROJ + 2304];
    #pragma unroll
    for (int off = 32; off; off >>= 1) s += __shfl_xor(s, off);
    if (lane == 0) {
        float raw = s + dt_bias[0];
        dts[row] = raw > 20.f ? raw : log1pf(expf(raw));
    }
}

// ---------- causal depthwise conv(4) + bias + SiLU ----------
__global__ void k_conv(const bf16* __restrict__ xBCin, const float* __restrict__ conv_w,
                       const float* __restrict__ conv_b, bf16* __restrict__ xBCa)
{
    int c   = blockIdx.x * 256 + threadIdx.x;   // 0..1279
    int row = blockIdx.y;
    int t   = row & (SEQ - 1);
    float acc = conv_b[c];
    #pragma unroll
    for (int j = 0; j < 4; ++j) {
        int tt = t - 3 + j;
        if (tt >= 0)
            acc = fmaf(fbf(xBCin[(size_t)(row - 3 + j) * CONV_DIM + c]), conv_w[c*4 + j], acc);
    }
    float v = acc / (1.f + expf(-acc));
    xBCa[(size_t)row * CONV_DIM + c] = tbf(v);
}

// ---------- per-chunk cumsum of a_t = A*dt, decay factors ----------
__global__ void k_prep(const float* __restrict__ dts, const float* __restrict__ A_log,
                       float* __restrict__ svec, float* __restrict__ wvec,
                       float* __restrict__ esvec, float* __restrict__ Pc)
{
    int chunk = blockIdx.x, t = threadIdx.x;  // 128 threads
    int row = chunk * CHUNK + t;
    float A = -expf(A_log[0]);
    __shared__ float sh[CHUNK];
    sh[t] = A * dts[row];
    __syncthreads();
    for (int off = 1; off < CHUNK; off <<= 1) {
        float v = (t >= off) ? sh[t - off] : 0.f;
        __syncthreads();
        sh[t] += v;
        __syncthreads();
    }
    float s = sh[t], sL = sh[CHUNK - 1];
    svec[row]  = s;
    wvec[row]  = expf(sL - s) * dts[row];
    esvec[row] = expf(s);
    if (t == CHUNK - 1) Pc[chunk] = expf(sL);
}

// ---------- Xt[chunk][p][l] = x_ssm transposed (bf16) ----------
__global__ void k_build_xt(const bf16* __restrict__ xBCa, bf16* __restrict__ Xt)
{
    __shared__ bf16 tile[32][33];
    int chunk = blockIdx.z;
    int p0 = blockIdx.x * 32, l0 = blockIdx.y * 32;
    int tx = threadIdx.x, ty = threadIdx.y;
    #pragma unroll
    for (int i = 0; i < 32; i += 8)
        tile[ty + i][tx] = xBCa[(size_t)(chunk*CHUNK + l0 + ty + i) * CONV_DIM + p0 + tx];
    __syncthreads();
    #pragma unroll
    for (int i = 0; i < 32; i += 8)
        Xt[(size_t)chunk * (D_INNER*CHUNK) + (size_t)(p0 + ty + i) * CHUNK + l0 + tx] = tile[tx][ty + i];
}

// ---------- Bw[chunk][n][l] = w_l * B[l][n] (bf16) ----------
__global__ void k_build_bw(const bf16* __restrict__ xBCa, const float* __restrict__ wvec,
                           bf16* __restrict__ Bw)
{
    __shared__ float tile[32][33];
    int chunk = blockIdx.z;
    int n0 = blockIdx.x * 32, l0 = blockIdx.y * 32;
    int tx = threadIdx.x, ty = threadIdx.y;
    #pragma unroll
    for (int i = 0; i < 32; i += 8) {
        int row = chunk*CHUNK + l0 + ty + i;
        tile[ty + i][tx] = fbf(xBCa[(size_t)row * CONV_DIM + D_INNER + n0 + tx]) * wvec[row];
    }
    __syncthreads();
    #pragma unroll
    for (int i = 0; i < 32; i += 8)
        Bw[(size_t)chunk * (D_STATE*CHUNK) + (size_t)(n0 + ty + i) * CHUNK + l0 + tx] = tbf(tile[tx][ty + i]);
}

// ---------- Csb[row][n] = exp(s_row) * C[row][n] (bf16) ----------
__global__ void k_build_cs(const bf16* __restrict__ xBCa, const float* __restrict__ esvec,
                           bf16* __restrict__ Csb)
{
    int i = blockIdx.x * 256 + threadIdx.x;  // over NROWS*128
    int row = i >> 7, n = i & 127;
    Csb[i] = tbf(esvec[row] * fbf(xBCa[(size_t)row * CONV_DIM + D_INNER + D_STATE + n]));
}

// ---------- Sm[chunk][t][u] = masked/scaled G + D on diagonal (bf16) ----------
__global__ void k_sm(const float* __restrict__ G, const float* __restrict__ svec,
                     const float* __restrict__ dts, const float* __restrict__ Dp,
                     bf16* __restrict__ Sm)
{
    int chunk = blockIdx.x, t = blockIdx.y, u = threadIdx.x;
    size_t base = (size_t)chunk * (CHUNK*CHUNK) + t * CHUNK + u;
    float v = 0.f;
    if (u <= t) {
        int rb = chunk * CHUNK;
        v = G[base] * expf(svec[rb + t] - svec[rb + u]) * dts[rb + u];
        if (u == t) v += Dp[0];
    }
    Sm[base] = tbf(v);
}

// ---------- sequential carry over 16 chunks per batch ----------
__global__ void k_carry(const bf16* __restrict__ dH, const float* __restrict__ Pc,
                        bf16* __restrict__ Hprev)
{
    int idx = blockIdx.x * 256 + threadIdx.x;   // 0..131071 (p*128+n)
    int b = blockIdx.y;
    float h = 0.f;
    for (int c = 0; c < SEQ/CHUNK; ++c) {
        int bi = b * (SEQ/CHUNK) + c;
        size_t o = (size_t)bi * (D_INNER*D_STATE) + idx;
        Hprev[o] = tbf(h);
        h = Pc[bi] * h + fbf(dH[o]);
    }
}

// ---------- gate (silu(z)) + RMSNorm -> bf16 ----------
__global__ __launch_bounds__(256) void k_gate_norm(
    const float* __restrict__ y, const bf16* __restrict__ zb,
    const float* __restrict__ norm_w, bf16* __restrict__ yb)
{
    int row = blockIdx.x;
    int tid = threadIdx.x;
    const float* yr = y + (size_t)row * D_INNER;
    const bf16*  zr = zb + (size_t)row * D_INNER;
    float4 v = *(const float4*)(yr + tid * 4);
    float z0 = fbf(zr[tid*4+0]), z1 = fbf(zr[tid*4+1]);
    float z2 = fbf(zr[tid*4+2]), z3 = fbf(zr[tid*4+3]);
    v.x *= z0 / (1.f + expf(-z0));
    v.y *= z1 / (1.f + expf(-z1));
    v.z *= z2 / (1.f + expf(-z2));
    v.w *= z3 / (1.f + expf(-z3));
    float ss = v.x*v.x + v.y*v.y + v.z*v.z + v.w*v.w;
    #pragma unroll
    for (int off = 32; off; off >>= 1) ss += __shfl_xor(ss, off);
    __shared__ float wsum[4];
    if ((tid & 63) == 0) wsum[tid >> 6] = ss;
    __syncthreads();
    float tot   = wsum[0] + wsum[1] + wsum[2] + wsum[3];
    float scale = rsqrtf(tot * (1.f / D_INNER) + EPS_RMS);
    yb[(size_t)row*D_INNER + tid*4+0] = tbf(v.x * scale * norm_w[tid*4+0]);
    yb[(size_t)row*D_INNER + tid*4+1] = tbf(v.y * scale * norm_w[tid*4+1]);
    yb[(size_t)row*D_INNER + tid*4+2] = tbf(v.z * scale * norm_w[tid*4+2]);
    yb[(size_t)row*D_INNER + tid*4+3] = tbf(v.w * scale * norm_w[tid*4+3]);
}

extern "C" void kernel_launch(void* const* d_in, const int* in_sizes, int n_in,
                              void* d_out, int out_size, void* d_ws, size_t ws_size,
                              hipStream_t stream)
{
    const float* x       = (const float*)d_in[0];
    const float* rnn     = (const float*)d_in[1];
    const float* W_in    = (const float*)d_in[2];
    const float* conv_w  = (const float*)d_in[3];
    const float* conv_b  = (const float*)d_in[4];
    const float* dt_bias = (const float*)d_in[5];
    const float* A_log   = (const float*)d_in[6];
    const float* Dp      = (const float*)d_in[7];
    const float* norm_w  = (const float*)d_in[8];
    const float* W_out   = (const float*)d_in[9];
    float* out = (float*)d_out;

    char* ws = (char*)d_ws;
    size_t off = 0;
    auto alloc = [&](size_t bytes) { void* p = ws + off; off += (bytes + 255) & ~255ULL; return p; };

    // ---- fixed buffers ----
    bf16*  W_inbT  = (bf16*) alloc((size_t)NPROJ * D_MODEL * 2);     // 2.36M
    bf16*  W_outbT = (bf16*) alloc((size_t)D_MODEL * D_INNER * 2);   // 1.05M
    float* dts     = (float*)alloc((size_t)NROWS * 4);
    float* svec    = (float*)alloc((size_t)NROWS * 4);
    float* wvec    = (float*)alloc((size_t)NROWS * 4);
    float* esvec   = (float*)alloc((size_t)NROWS * 4);
    float* Pc      = (float*)alloc((size_t)NCHUNK * 4);
    bf16*  zb      = (bf16*) alloc((size_t)NROWS * D_INNER * 2);     // 33.5M
    bf16*  Smb     = (bf16*) alloc((size_t)NCHUNK * CHUNK*CHUNK * 2);// 4.2M
    bf16*  Csb     = (bf16*) alloc((size_t)NROWS * D_STATE * 2);     // 4.2M
    bf16*  Bw      = (bf16*) alloc((size_t)NCHUNK * D_STATE*CHUNK * 2); // 4.2M
    // ---- aliased regions (liveness-checked) ----
    char* R1 = (char*)alloc((size_t)NROWS * D_INNER * 4);            // 67.1M
    bf16*  xBCin = (bf16*)R1;   // [GEMM1, conv]
    float* yf    = (float*)R1;  // [Y_intra, gate_norm]
    char* R2 = (char*)alloc((size_t)NROWS * CONV_DIM * 2);           // 41.9M
    bf16*  xBCa  = (bf16*)R2;   // [conv, builds/G-GEMM]
    bf16*  dH    = (bf16*)R2;   // [dH-GEMM, carry]  (33.5M)
    char* R3 = (char*)alloc((size_t)NCHUNK * D_INNER*D_STATE * 2);   // 33.5M
    bf16*  xb    = (bf16*)R3;   // [cvt, GEMM1]      (16.8M)
    float* Gbuf  = (float*)R3;  // [G-GEMM, k_sm]    (8.4M)
    bf16*  Hprev = (bf16*)R3;   // [carry, Y_inter]  (33.5M)
    char* R4 = (char*)alloc((size_t)NROWS * D_INNER * 2);            // 33.5M
    bf16*  Xt    = (bf16*)R4;   // [build_xt, Y_intra]
    bf16*  yb    = (bf16*)R4;   // [gate_norm, GEMM2]
    // total ~226.0 MB (round 1 proved >= 238.4 MB available)

    // 1. converts / weight transposes / dt GEMV
    k_cvt_bf16<<<(NROWS * D_MODEL / 4 + 255) / 256, 256, 0, stream>>>(x, xb, NROWS * D_MODEL);
    k_transpose_cvt<<<dim3(D_MODEL/32, NPROJ/32), dim3(32, 8), 0, stream>>>(
        W_in, W_inbT, NPROJ, D_MODEL, D_IN_PROJ);
    k_transpose_cvt<<<dim3(D_INNER/32, D_MODEL/32), dim3(32, 8), 0, stream>>>(
        W_out, W_outbT, D_MODEL, D_INNER, D_MODEL);
    k_dt<<<NROWS / 4, 256, 0, stream>>>(x, W_in, dt_bias, dts);

    // 2. in-projection GEMM with split output
    k_gemm_in<<<dim3(NROWS/128, NPROJ/128), 256, 0, stream>>>(xb, W_inbT, zb, xBCin, D_MODEL);

    // 3. causal depthwise conv + silu
    k_conv<<<dim3(CONV_DIM/256, NROWS), 256, 0, stream>>>(xBCin, conv_w, conv_b, xBCa);

    // 4. SSD prep: cumsums + operand builds
    k_prep<<<NCHUNK, CHUNK, 0, stream>>>(dts, A_log, svec, wvec, esvec, Pc);
    k_build_xt<<<dim3(32, 4, NCHUNK), dim3(32, 8), 0, stream>>>(xBCa, Xt);
    k_build_bw<<<dim3(4, 4, NCHUNK), dim3(32, 8), 0, stream>>>(xBCa, wvec, Bw);
    k_build_cs<<<NROWS * D_STATE / 256, 256, 0, stream>>>(xBCa, esvec, Csb);

    // 5. G = C @ B^T  (per chunk 128x128, K=128)
    k_bgemm<0,0><<<dim3(1, 1, NCHUNK), 256, 0, stream>>>(
        xBCa + D_INNER + D_STATE, CONV_DIM, (size_t)CHUNK*CONV_DIM,
        xBCa + D_INNER,           CONV_DIM, (size_t)CHUNK*CONV_DIM,
        Gbuf, CHUNK, (size_t)CHUNK*CHUNK, CHUNK);

    // 6. mask/scale G (+D on diagonal)
    k_sm<<<dim3(NCHUNK, CHUNK), CHUNK, 0, stream>>>(Gbuf, svec, dts, Dp, Smb);

    // 7. dH = X^T @ Bw^T  (per chunk 1024x128, K=128)
    k_bgemm<1,0><<<dim3(D_INNER/128, 1, NCHUNK), 256, 0, stream>>>(
        Xt, CHUNK, (size_t)D_INNER*CHUNK,
        Bw, CHUNK, (size_t)D_STATE*CHUNK,
        dH, D_STATE, (size_t)D_INNER*D_STATE, CHUNK);

    // 8. carry states across chunks
    k_carry<<<dim3(D_INNER*D_STATE/256, BATCH), 256, 0, stream>>>(dH, Pc, Hprev);

    // 9. Y_intra = Sm @ X  -> yf
    k_bgemm<0,0><<<dim3(1, D_INNER/128, NCHUNK), 256, 0, stream>>>(
        Smb, CHUNK, (size_t)CHUNK*CHUNK,
        Xt,  CHUNK, (size_t)D_INNER*CHUNK,
        yf, D_INNER, (size_t)CHUNK*D_INNER, CHUNK);

    // 10. Y_inter = Cs @ Hprev^T  accumulated into yf
    k_bgemm<0,1><<<dim3(1, D_INNER/128, NCHUNK), 256, 0, stream>>>(
        Csb,   D_STATE, (size_t)CHUNK*D_STATE,
        Hprev, D_STATE, (size_t)D_INNER*D_STATE,
        yf, D_INNER, (size_t)CHUNK*D_INNER, CHUNK);

    // 11. gate + RMSNorm
    k_gate_norm<<<NROWS, 256, 0, stream>>>(yf, zb, norm_w, yb);

    // 12. out-projection GEMM -> d_out
    k_bgemm<0,0><<<dim3(NROWS/128, D_MODEL/128, 1), 256, 0, stream>>>(
        yb, D_INNER, 0, W_outbT, D_INNER, 0, out, D_MODEL, 0, D_INNER);

    // 13. rnn_state passthrough
    hipMemcpyAsync(out + (size_t)NROWS * D_MODEL, rnn,
                   (size_t)BATCH * D_MODEL * sizeof(float),
                   hipMemcpyDeviceToDevice, stream);
}

// Round 3
// 347.396 us; speedup vs baseline: 3.5122x; 1.4219x over previous
//
#include <hip/hip_runtime.h>
#include <hip/hip_bf16.h>
#include <math.h>

#define D_MODEL 512
#define D_INNER 1024
#define D_STATE 128
#define CONV_DIM (D_INNER + 2*D_STATE)        // 1280
#define D_IN_PROJ (2*D_INNER + 2*D_STATE + 1) // 2305
#define NPROJ 2304                            // z + xBC cols (dt col via GEMV)
#define BATCH 8
#define SEQ 2048
#define NROWS (BATCH*SEQ)                     // 16384
#define CHUNK 128
#define NCHUNK (NROWS/CHUNK)                  // 128 total (16 per batch)
#define CPB (SEQ/CHUNK)                       // 16 chunks per batch
#define EPS_RMS 1e-5f

typedef __hip_bfloat16 bf16;
typedef __attribute__((ext_vector_type(8))) short short8;
typedef __attribute__((ext_vector_type(4))) float f32x4;

__device__ __forceinline__ float fbf(bf16 v) { return __bfloat162float(v); }
__device__ __forceinline__ bf16 tbf(float v) { return __float2bfloat16(v); }

// ---------- transpose + convert: dst[r][c] = bf16(src[c*sstride + r]) ----------
__global__ void k_transpose_cvt(const float* __restrict__ src, bf16* __restrict__ dst,
                                int R, int C, int sstride) {
    __shared__ float tile[32][33];
    int c0 = blockIdx.x * 32, r0 = blockIdx.y * 32;
    int tx = threadIdx.x, ty = threadIdx.y;
    #pragma unroll
    for (int i = 0; i < 32; i += 8)
        tile[ty + i][tx] = src[(size_t)(c0 + ty + i) * sstride + (r0 + tx)];
    __syncthreads();
    #pragma unroll
    for (int i = 0; i < 32; i += 8)
        dst[(size_t)(r0 + ty + i) * C + (c0 + tx)] = tbf(tile[tx][ty + i]);
}

// ---------- fused x->bf16 convert + dt GEMV + softplus ----------
__global__ __launch_bounds__(256) void k_dtcvt(
    const float* __restrict__ x, const float* __restrict__ W_in,
    const float* __restrict__ dt_bias,
    bf16* __restrict__ xb, float* __restrict__ dts)
{
    __shared__ float wcol[D_MODEL];
    int tid = threadIdx.x;
    wcol[tid]       = W_in[(size_t)tid * D_IN_PROJ + 2304];
    wcol[tid + 256] = W_in[(size_t)(tid + 256) * D_IN_PROJ + 2304];
    __syncthreads();
    int row  = blockIdx.x * 4 + (tid >> 6);
    int lane = tid & 63;
    const float* xr = x + (size_t)row * D_MODEL;
    float4 a = *(const float4*)(xr + lane * 8);
    float4 b = *(const float4*)(xr + lane * 8 + 4);
    union { bf16 o[8]; uint4 u; } pk;
    pk.o[0]=tbf(a.x); pk.o[1]=tbf(a.y); pk.o[2]=tbf(a.z); pk.o[3]=tbf(a.w);
    pk.o[4]=tbf(b.x); pk.o[5]=tbf(b.y); pk.o[6]=tbf(b.z); pk.o[7]=tbf(b.w);
    *(uint4*)(xb + (size_t)row * D_MODEL + lane * 8) = pk.u;
    const float* wc = wcol + lane * 8;
    float s = a.x*wc[0]+a.y*wc[1]+a.z*wc[2]+a.w*wc[3]
            + b.x*wc[4]+b.y*wc[5]+b.z*wc[6]+b.w*wc[7];
    #pragma unroll
    for (int off = 32; off; off >>= 1) s += __shfl_xor(s, off);
    if (lane == 0) {
        float raw = s + dt_bias[0];
        dts[row] = raw > 20.f ? raw : log1pf(expf(raw));
    }
}

// ---------- batched NT GEMM, 128x128 tile, BK=64 ----------
// C[bi][M][N] = A[bi][M][K] @ Bt[bi][N][K]^T
template<int OUTBF>
__global__ __launch_bounds__(256) void k_bgemm(
    const bf16* __restrict__ A, int lda, size_t sA,
    const bf16* __restrict__ Bt, int ldb, size_t sB,
    void* __restrict__ Cv, int ldc, size_t sC, int K)
{
    constexpr int BK = 64, LDK = BK + 8;
    __shared__ __align__(16) bf16 As[128][LDK];
    __shared__ __align__(16) bf16 Bs[128][LDK];
    const int tid = threadIdx.x, lane = tid & 63, wave = tid >> 6;
    const int wm = (wave & 1) * 64, wn = (wave >> 1) * 64;
    const int lr = lane & 15, quad = lane >> 4;
    const size_t bm = (size_t)blockIdx.x * 128;
    const size_t bn = (size_t)blockIdx.y * 128;
    const size_t bi = blockIdx.z;
    A  += bi * sA;
    Bt += bi * sB;

    f32x4 acc[4][4];
    #pragma unroll
    for (int i = 0; i < 4; ++i)
        #pragma unroll
        for (int j = 0; j < 4; ++j) acc[i][j] = (f32x4){0.f,0.f,0.f,0.f};

    for (int k0 = 0; k0 < K; k0 += BK) {
        __syncthreads();
        #pragma unroll
        for (int i = 0; i < 4; ++i) {
            int c = tid + 256 * i;
            int r = c >> 3, col = (c & 7) << 3;
            *(uint4*)(&As[r][col]) = *(const uint4*)(A  + (bm + r) * lda + k0 + col);
            *(uint4*)(&Bs[r][col]) = *(const uint4*)(Bt + (bn + r) * ldb + k0 + col);
        }
        __syncthreads();
        #pragma unroll
        for (int ks = 0; ks < BK; ks += 32) {
            short8 af[4], bg[4];
            #pragma unroll
            for (int i = 0; i < 4; ++i)
                af[i] = *(const short8*)(&As[wm + i*16 + lr][ks + quad*8]);
            #pragma unroll
            for (int j = 0; j < 4; ++j)
                bg[j] = *(const short8*)(&Bs[wn + j*16 + lr][ks + quad*8]);
            #pragma unroll
            for (int i = 0; i < 4; ++i)
                #pragma unroll
                for (int j = 0; j < 4; ++j)
                    acc[i][j] = __builtin_amdgcn_mfma_f32_16x16x32_bf16(af[i], bg[j], acc[i][j], 0,0,0);
        }
    }
    #pragma unroll
    for (int i = 0; i < 4; ++i)
        #pragma unroll
        for (int j = 0; j < 4; ++j)
            #pragma unroll
            for (int r = 0; r < 4; ++r) {
                size_t row = bm + wm + i*16 + quad*4 + r;
                size_t col = bn + wn + j*16 + lr;
                float v = acc[i][j][r];
                if (OUTBF) ((bf16*)Cv + bi*sC)[row * ldc + col] = tbf(v);
                else       ((float*)Cv + bi*sC)[row * ldc + col] = v;
            }
}

// ---------- GEMM1 with split output: cols<1024 -> zb, else xBCin ----------
__global__ __launch_bounds__(256) void k_gemm_in(
    const bf16* __restrict__ A, const bf16* __restrict__ Bt,
    bf16* __restrict__ zb, bf16* __restrict__ xBCin, int K)
{
    constexpr int BK = 64, LDK = BK + 8;
    __shared__ __align__(16) bf16 As[128][LDK];
    __shared__ __align__(16) bf16 Bs[128][LDK];
    const int tid = threadIdx.x, lane = tid & 63, wave = tid >> 6;
    const int wm = (wave & 1) * 64, wn = (wave >> 1) * 64;
    const int lr = lane & 15, quad = lane >> 4;
    const size_t bm = (size_t)blockIdx.x * 128;
    const int bn = blockIdx.y * 128;

    f32x4 acc[4][4];
    #pragma unroll
    for (int i = 0; i < 4; ++i)
        #pragma unroll
        for (int j = 0; j < 4; ++j) acc[i][j] = (f32x4){0.f,0.f,0.f,0.f};

    for (int k0 = 0; k0 < K; k0 += BK) {
        __syncthreads();
        #pragma unroll
        for (int i = 0; i < 4; ++i) {
            int c = tid + 256 * i;
            int r = c >> 3, col = (c & 7) << 3;
            *(uint4*)(&As[r][col]) = *(const uint4*)(A  + (bm + r) * K + k0 + col);
            *(uint4*)(&Bs[r][col]) = *(const uint4*)(Bt + ((size_t)bn + r) * K + k0 + col);
        }
        __syncthreads();
        #pragma unroll
        for (int ks = 0; ks < BK; ks += 32) {
            short8 af[4], bg[4];
            #pragma unroll
            for (int i = 0; i < 4; ++i)
                af[i] = *(const short8*)(&As[wm + i*16 + lr][ks + quad*8]);
            #pragma unroll
            for (int j = 0; j < 4; ++j)
                bg[j] = *(const short8*)(&Bs[wn + j*16 + lr][ks + quad*8]);
            #pragma unroll
            for (int i = 0; i < 4; ++i)
                #pragma unroll
                for (int j = 0; j < 4; ++j)
                    acc[i][j] = __builtin_amdgcn_mfma_f32_16x16x32_bf16(af[i], bg[j], acc[i][j], 0,0,0);
        }
    }
    #pragma unroll
    for (int i = 0; i < 4; ++i)
        #pragma unroll
        for (int j = 0; j < 4; ++j)
            #pragma unroll
            for (int r = 0; r < 4; ++r) {
                size_t row = bm + wm + i*16 + quad*4 + r;
                int col = bn + wn + j*16 + lr;
                float v = acc[i][j][r];
                if (col < D_INNER) zb[row * D_INNER + col] = tbf(v);
                else xBCin[row * CONV_DIM + (col - D_INNER)] = tbf(v);
            }
}

// ---------- per-chunk cumsum of a_t = A*dt, decay factors ----------
__global__ void k_prep(const float* __restrict__ dts, const float* __restrict__ A_log,
                       float* __restrict__ svec, float* __restrict__ wvec,
                       float* __restrict__ esvec, float* __restrict__ Pc)
{
    int chunk = blockIdx.x, t = threadIdx.x;  // 128 threads
    int row = chunk * CHUNK + t;
    float A = -expf(A_log[0]);
    __shared__ float sh[CHUNK];
    sh[t] = A * dts[row];
    __syncthreads();
    for (int off = 1; off < CHUNK; off <<= 1) {
        float v = (t >= off) ? sh[t - off] : 0.f;
        __syncthreads();
        sh[t] += v;
        __syncthreads();
    }
    float s = sh[t], sL = sh[CHUNK - 1];
    svec[row]  = s;
    wvec[row]  = expf(sL - s) * dts[row];
    esvec[row] = expf(s);
    if (t == CHUNK - 1) Pc[chunk] = expf(sL);
}

// ---------- conv+silu for x-region, writes Xt directly into B2[:, 0:128] ----------
// grid (8, NCHUNK), block 256. Block = chunk x 128-channel tile.
__global__ __launch_bounds__(256) void k_conv_x(
    const bf16* __restrict__ xBCin, const float* __restrict__ conv_w,
    const float* __restrict__ conv_b, bf16* __restrict__ B2)
{
    __shared__ __align__(16) bf16 Ls[131][128];
    const int chunk = blockIdx.y;
    const int p0 = blockIdx.x * 128;
    const int tid = threadIdx.x;
    const bool first = (chunk % CPB) == 0;
    const size_t rowbase = (size_t)chunk * CHUNK;
    for (int i = tid; i < 131 * 16; i += 256) {
        int r = i >> 4, cg = (i & 15) << 3;
        uint4 v = (uint4){0,0,0,0};
        if (!(first && r < 3))
            v = *(const uint4*)(xBCin + (rowbase + r - 3) * CONV_DIM + p0 + cg);
        *(uint4*)(&Ls[r][cg]) = v;
    }
    __syncthreads();
    const int p = tid & 127;
    const int half = tid >> 7;
    const int ch = p0 + p;
    float4 w = *(const float4*)(conv_w + ch * 4);
    float bias = conv_b[ch];
    bf16* outrow = B2 + (size_t)chunk * (D_INNER * 256) + (size_t)ch * 256;
    float xv[11];
    #pragma unroll
    for (int i = 0; i < 3; ++i) xv[i + 8] = fbf(Ls[half * 64 + i][p]);
    for (int v = 0; v < 8; ++v) {
        int t0 = half * 64 + v * 8;
        xv[0]=xv[8]; xv[1]=xv[9]; xv[2]=xv[10];
        #pragma unroll
        for (int i = 3; i < 11; ++i) xv[i] = fbf(Ls[t0 + i][p]);
        union { bf16 o[8]; uint4 u; } pk;
        #pragma unroll
        for (int j = 0; j < 8; ++j) {
            float a = bias + w.x*xv[j] + w.y*xv[j+1] + w.z*xv[j+2] + w.w*xv[j+3];
            pk.o[j] = tbf(a / (1.f + expf(-a)));
        }
        *(uint4*)(outrow + t0) = pk.u;
    }
}

// ---------- conv+silu for B/C region: raw B, raw C, scaled Bw^T, scaled Cs ----------
// grid NCHUNK, block 256 (128 B-channels + 128 C-channels)
__global__ __launch_bounds__(256) void k_conv_bc(
    const bf16* __restrict__ xBCin, const float* __restrict__ conv_w,
    const float* __restrict__ conv_b, const float* __restrict__ wvec,
    const float* __restrict__ esvec,
    bf16* __restrict__ Braw, bf16* __restrict__ Craw,
    bf16* __restrict__ Bw, bf16* __restrict__ A2)
{
    __shared__ __align__(16) bf16 Ls[131][256];
    const int chunk = blockIdx.x;
    const bool first = (chunk % CPB) == 0;
    const size_t rowbase = (size_t)chunk * CHUNK;
    for (int i = threadIdx.x; i < 131 * 32; i += 256) {
        int r = i >> 5, cg = (i & 31) << 3;
        uint4 v = (uint4){0,0,0,0};
        if (!(first && r < 3))
            v = *(const uint4*)(xBCin + (rowbase + r - 3) * CONV_DIM + D_INNER + cg);
        *(uint4*)(&Ls[r][cg]) = v;
    }
    __syncthreads();
    const int n   = threadIdx.x & 127;
    const int reg = threadIdx.x >> 7;  // 0 = B, 1 = C
    const int cl  = reg * 128 + n;
    const int ch  = D_INNER + cl;
    float4 w = *(const float4*)(conv_w + ch * 4);
    float bias = conv_b[ch];
    float xv[11];
    #pragma unroll
    for (int i = 0; i < 3; ++i) xv[i + 8] = fbf(Ls[i][cl]);
    for (int v = 0; v < 16; ++v) {
        int t0 = v * 8;
        xv[0]=xv[8]; xv[1]=xv[9]; xv[2]=xv[10];
        #pragma unroll
        for (int i = 3; i < 11; ++i) xv[i] = fbf(Ls[t0 + i][cl]);
        float o[8];
        #pragma unroll
        for (int j = 0; j < 8; ++j) {
            float a = bias + w.x*xv[j] + w.y*xv[j+1] + w.z*xv[j+2] + w.w*xv[j+3];
            o[j] = a / (1.f + expf(-a));
        }
        if (reg == 0) {
            union { bf16 ob[8]; uint4 u; } pk;
            #pragma unroll
            for (int j = 0; j < 8; ++j) {
                Braw[(size_t)chunk*(CHUNK*D_STATE) + (size_t)(t0+j)*D_STATE + n] = tbf(o[j]);
                pk.ob[j] = tbf(o[j] * wvec[rowbase + t0 + j]);
            }
            *(uint4*)(Bw + (size_t)chunk*(D_STATE*CHUNK) + (size_t)n*CHUNK + t0) = pk.u;
        } else {
            #pragma unroll
            for (int j = 0; j < 8; ++j) {
                Craw[(size_t)chunk*(CHUNK*D_STATE) + (size_t)(t0+j)*D_STATE + n] = tbf(o[j]);
                A2[(size_t)chunk*(CHUNK*256) + (size_t)(t0+j)*256 + 128 + n] =
                    tbf(o[j] * esvec[rowbase + t0 + j]);
            }
        }
    }
}

// ---------- Sm[t][u] into A2[:, 0:128]: masked/scaled G + D on diagonal ----------
__global__ void k_sm(const float* __restrict__ G, const float* __restrict__ svec,
                     const float* __restrict__ dts, const float* __restrict__ Dp,
                     bf16* __restrict__ A2)
{
    int chunk = blockIdx.x, t = blockIdx.y, u = threadIdx.x;
    float v = 0.f;
    if (u <= t) {
        int rb = chunk * CHUNK;
        v = G[(size_t)chunk*(CHUNK*CHUNK) + t*CHUNK + u]
            * expf(svec[rb + t] - svec[rb + u]) * dts[rb + u];
        if (u == t) v += Dp[0];
    }
    A2[(size_t)chunk*(CHUNK*256) + (size_t)t*256 + u] = tbf(v);
}

// ---------- sequential carry over 16 chunks/batch, writes Hprev into B2[:, 128:256] ----------
__global__ void k_carry(const bf16* __restrict__ dH, const float* __restrict__ Pc,
                        bf16* __restrict__ B2)
{
    int idx = blockIdx.x * 256 + threadIdx.x;   // p*128+n
    int b = blockIdx.y;
    int p = idx >> 7, n = idx & 127;
    float h = 0.f;
    for (int c = 0; c < CPB; ++c) {
        int bi = b * CPB + c;
        B2[(size_t)bi * (D_INNER*256) + (size_t)p * 256 + 128 + n] = tbf(h);
        h = Pc[bi] * h + fbf(dH[(size_t)bi * (D_INNER*D_STATE) + idx]);
    }
}

// ---------- gate (silu(z)) + RMSNorm -> bf16 ----------
__global__ __launch_bounds__(256) void k_gate_norm(
    const float* __restrict__ y, const bf16* __restrict__ zb,
    const float* __restrict__ norm_w, bf16* __restrict__ yb)
{
    int row = blockIdx.x;
    int tid = threadIdx.x;
    const float* yr = y + (size_t)row * D_INNER;
    const bf16*  zr = zb + (size_t)row * D_INNER;
    float4 v = *(const float4*)(yr + tid * 4);
    float z0 = fbf(zr[tid*4+0]), z1 = fbf(zr[tid*4+1]);
    float z2 = fbf(zr[tid*4+2]), z3 = fbf(zr[tid*4+3]);
    v.x *= z0 / (1.f + expf(-z0));
    v.y *= z1 / (1.f + expf(-z1));
    v.z *= z2 / (1.f + expf(-z2));
    v.w *= z3 / (1.f + expf(-z3));
    float ss = v.x*v.x + v.y*v.y + v.z*v.z + v.w*v.w;
    #pragma unroll
    for (int off = 32; off; off >>= 1) ss += __shfl_xor(ss, off);
    __shared__ float wsum[4];
    if ((tid & 63) == 0) wsum[tid >> 6] = ss;
    __syncthreads();
    float tot   = wsum[0] + wsum[1] + wsum[2] + wsum[3];
    float scale = rsqrtf(tot * (1.f / D_INNER) + EPS_RMS);
    yb[(size_t)row*D_INNER + tid*4+0] = tbf(v.x * scale * norm_w[tid*4+0]);
    yb[(size_t)row*D_INNER + tid*4+1] = tbf(v.y * scale * norm_w[tid*4+1]);
    yb[(size_t)row*D_INNER + tid*4+2] = tbf(v.z * scale * norm_w[tid*4+2]);
    yb[(size_t)row*D_INNER + tid*4+3] = tbf(v.w * scale * norm_w[tid*4+3]);
}

extern "C" void kernel_launch(void* const* d_in, const int* in_sizes, int n_in,
                              void* d_out, int out_size, void* d_ws, size_t ws_size,
                              hipStream_t stream)
{
    const float* x       = (const float*)d_in[0];
    const float* rnn     = (const float*)d_in[1];
    const float* W_in    = (const float*)d_in[2];
    const float* conv_w  = (const float*)d_in[3];
    const float* conv_b  = (const float*)d_in[4];
    const float* dt_bias = (const float*)d_in[5];
    const float* A_log   = (const float*)d_in[6];
    const float* Dp      = (const float*)d_in[7];
    const float* norm_w  = (const float*)d_in[8];
    const float* W_out   = (const float*)d_in[9];
    float* out = (float*)d_out;

    char* ws = (char*)d_ws;
    size_t off = 0;
    auto alloc = [&](size_t bytes) { void* p = ws + off; off += (bytes + 255) & ~255ULL; return p; };

    // ---- persistent ----
    bf16*  W_inbT  = (bf16*) alloc((size_t)NPROJ * D_MODEL * 2);        // 2.36M
    bf16*  W_outbT = (bf16*) alloc((size_t)D_MODEL * D_INNER * 2);      // 1.05M
    float* dts     = (float*)alloc((size_t)NROWS * 4);
    float* svec    = (float*)alloc((size_t)NROWS * 4);
    float* wvec    = (float*)alloc((size_t)NROWS * 4);
    float* esvec   = (float*)alloc((size_t)NROWS * 4);
    float* Pc      = (float*)alloc((size_t)NCHUNK * 4);
    bf16*  zb      = (bf16*) alloc((size_t)NROWS * D_INNER * 2);        // 33.5M
    bf16*  A2      = (bf16*) alloc((size_t)NCHUNK * CHUNK * 256 * 2);   // 8.4M  [Sm | Cs]
    bf16*  B2      = (bf16*) alloc((size_t)NCHUNK * D_INNER * 256 * 2); // 67.1M [Xt | Hprev]
    bf16*  Bw      = (bf16*) alloc((size_t)NCHUNK * D_STATE * CHUNK * 2);  // 4.2M
    bf16*  Braw    = (bf16*) alloc((size_t)NCHUNK * CHUNK * D_STATE * 2); // 4.2M
    bf16*  Craw    = (bf16*) alloc((size_t)NCHUNK * CHUNK * D_STATE * 2); // 4.2M
    // ---- aliased region A (67.1M): xb[0:16.8] + dH[16.8:50.3], later yf[0:67.1] ----
    char* RA = (char*)alloc((size_t)NROWS * D_INNER * 4);
    bf16*  xb   = (bf16*)RA;                                   // [dtcvt -> GEMM1]
    bf16*  dH   = (bf16*)(RA + (size_t)NROWS * D_MODEL * 2);   // [dH-GEMM -> carry]
    float* yf   = (float*)RA;                                  // [Y-GEMM -> gate_norm]
    // ---- aliased region B (41.9M): xBCin, later yb[0:33.5] + Gbuf[33.5:41.9] ----
    char* RB = (char*)alloc((size_t)NROWS * CONV_DIM * 2);
    bf16*  xBCin = (bf16*)RB;                                  // [GEMM1 -> convs]
    bf16*  yb    = (bf16*)RB;                                  // [gate_norm -> GEMM2]
    float* Gbuf  = (float*)(RB + (size_t)NROWS * D_INNER * 2); // [G-GEMM -> k_sm]
    // total ~234.3 MB (238.4 proven available in R1)

    // 1. fused convert + dt GEMV; weight transposes; cumsum prep
    k_dtcvt<<<NROWS / 4, 256, 0, stream>>>(x, W_in, dt_bias, xb, dts);
    k_transpose_cvt<<<dim3(D_MODEL/32, NPROJ/32), dim3(32, 8), 0, stream>>>(
        W_in, W_inbT, NPROJ, D_MODEL, D_IN_PROJ);
    k_transpose_cvt<<<dim3(D_INNER/32, D_MODEL/32), dim3(32, 8), 0, stream>>>(
        W_out, W_outbT, D_MODEL, D_INNER, D_MODEL);
    k_prep<<<NCHUNK, CHUNK, 0, stream>>>(dts, A_log, svec, wvec, esvec, Pc);

    // 2. in-projection GEMM with split output
    k_gemm_in<<<dim3(NROWS/128, NPROJ/128), 256, 0, stream>>>(xb, W_inbT, zb, xBCin, D_MODEL);

    // 3. conv + silu, fused with operand builds
    k_conv_x<<<dim3(8, NCHUNK), 256, 0, stream>>>(xBCin, conv_w, conv_b, B2);
    k_conv_bc<<<NCHUNK, 256, 0, stream>>>(xBCin, conv_w, conv_b, wvec, esvec,
                                          Braw, Craw, Bw, A2);

    // 4. G = C @ B^T  (per chunk 128x128, K=128)
    k_bgemm<0><<<dim3(1, 1, NCHUNK), 256, 0, stream>>>(
        Craw, D_STATE, (size_t)CHUNK*D_STATE,
        Braw, D_STATE, (size_t)CHUNK*D_STATE,
        Gbuf, CHUNK, (size_t)CHUNK*CHUNK, CHUNK);

    // 5. mask/scale G (+D diag) -> A2[:, 0:128]
    k_sm<<<dim3(NCHUNK, CHUNK), CHUNK, 0, stream>>>(Gbuf, svec, dts, Dp, A2);

    // 6. dH = X^T @ Bw^T  (A = Xt region of B2, lda=256)
    k_bgemm<1><<<dim3(D_INNER/128, 1, NCHUNK), 256, 0, stream>>>(
        B2, 256, (size_t)D_INNER*256,
        Bw, CHUNK, (size_t)D_STATE*CHUNK,
        dH, D_STATE, (size_t)D_INNER*D_STATE, CHUNK);

    // 7. carry states -> Hprev region of B2
    k_carry<<<dim3(D_INNER*D_STATE/256, BATCH), 256, 0, stream>>>(dH, Pc, B2);

    // 8. Y = [Sm|Cs] @ [Xt|Hprev]^T  (K=256) -> yf
    k_bgemm<0><<<dim3(1, D_INNER/128, NCHUNK), 256, 0, stream>>>(
        A2, 256, (size_t)CHUNK*256,
        B2, 256, (size_t)D_INNER*256,
        yf, D_INNER, (size_t)CHUNK*D_INNER, 256);

    // 9. gate + RMSNorm
    k_gate_norm<<<NROWS, 256, 0, stream>>>(yf, zb, norm_w, yb);

    // 10. out-projection GEMM -> d_out
    k_bgemm<0><<<dim3(NROWS/128, D_MODEL/128, 1), 256, 0, stream>>>(
        yb, D_INNER, 0, W_outbT, D_INNER, 0, out, D_MODEL, 0, D_INNER);

    // 11. rnn_state passthrough
    hipMemcpyAsync(out + (size_t)NROWS * D_MODEL, rnn,
                   (size_t)BATCH * D_MODEL * sizeof(float),
                   hipMemcpyDeviceToDevice, stream);
}